// Round 1
// baseline (771.931 us; speedup 1.0000x reference)
//
#include <hip/hip_runtime.h>
#include <hip/hip_bf16.h>
#include <cstdint>
#include <cstddef>

typedef __bf16 bf16_t;
typedef __bf16 bf16x8 __attribute__((ext_vector_type(8)));
typedef float  f32x4  __attribute__((ext_vector_type(4)));

#define N_ROWS 65536   // BS*CLIP
#define IN_CH  1024
#define OUT_CH 512
#define T_DIM  512
#define BS_    8192

// ---- async global->LDS, 16B per lane (global_load_lds_dwordx4) ----
__device__ __forceinline__ void async_copy16(const bf16_t* g, bf16_t* l) {
    __builtin_amdgcn_global_load_lds(
        (const __attribute__((address_space(1))) void*)(uintptr_t)(g),
        (__attribute__((address_space(3))) void*)(uintptr_t)(l),
        16, 0, 0);
}

// ---- fp32 -> bf16 pack, 8 elems/thread (weights only now) ----
__global__ __launch_bounds__(256)
void cvt_f32_bf16(const float* __restrict__ in, bf16_t* __restrict__ out, long n8) {
    long idx = (long)blockIdx.x * 256 + threadIdx.x;
    if (idx >= n8) return;
    const float4* p = (const float4*)(in + idx * 8);
    float4 u = p[0], v = p[1];
    bf16x8 o;
    o[0] = (__bf16)u.x; o[1] = (__bf16)u.y; o[2] = (__bf16)u.z; o[3] = (__bf16)u.w;
    o[4] = (__bf16)v.x; o[5] = (__bf16)v.y; o[6] = (__bf16)v.z; o[7] = (__bf16)v.w;
    *(bf16x8*)(out + idx * 8) = o;
}

// ---- m97-style GEMM: C[M,N] = A[M,K] * B[N,K]^T (+bias) ----
// AT = bf16_t : A staged via global_load_lds (async)
// AT = float  : A loaded fp32 to regs, cvt to bf16, ds_write (fused conversion)
// BIAS_MODE 0: + bias[col]
// BIAS_MODE 1: + bias2[(row>>3)*N + col]   (per-batch time-emb row, b_down folded in)
// BIAS_MODE 2: + bias[col] + bias2[col]
template<int BIAS_MODE, typename CT, typename AT>
__global__ __launch_bounds__(256, 2)
void gemm_bt(const AT* __restrict__ A, const bf16_t* __restrict__ B,
             CT* __restrict__ C,
             const float* __restrict__ bias,
             const float* __restrict__ bias2,
             int M, int N, int K)
{
    __shared__ bf16_t sA[128 * 32];
    __shared__ bf16_t sB[128 * 32];

    const int tid  = threadIdx.x;
    const int wave = tid >> 6;
    const int lane = tid & 63;

    // XCD-aware bijective swizzle (nwg % 8 == 0 for all our launches):
    // dispatch d lands on XCD d%8; remap so each XCD computes a contiguous
    // run of tile ids => all col-tiles of one 128-row A panel live on ONE
    // XCD's L2 (panel <= 512 KB << 4 MiB), back-to-back in time.
    const unsigned gx  = gridDim.x;
    const unsigned nwg = gx * gridDim.y;
    unsigned bid = blockIdx.y * gx + blockIdx.x;
    if ((nwg & 7u) == 0u) bid = (bid & 7u) * (nwg >> 3) + (bid >> 3);
    const int row0 = (int)(bid / gx) * 128;
    const int col0 = (int)(bid % gx) * 128;

    const int wr = (wave >> 1) * 64;
    const int wc = (wave & 1) * 64;

    f32x4 acc[4][4];
    #pragma unroll
    for (int i = 0; i < 4; ++i)
        #pragma unroll
        for (int j = 0; j < 4; ++j)
            acc[i][j] = (f32x4){0.f, 0.f, 0.f, 0.f};

    // staging: 8 segments of 1KB each for A and B; wave w does segs {2w, 2w+1}
    const int seg0  = wave * 2;
    const int srow  = lane >> 2;         // row within 16-row segment
    const int schnk = (lane & 3) * 8;    // k-elem offset (16B chunks bf16 / 32B fp32)

    const bf16_t* Bbase = B + (size_t)col0 * K + (size_t)srow * K + schnk;

    const bf16_t* Abase16 = nullptr;
    const float*  Abase32 = nullptr;
    if constexpr (sizeof(AT) == 2)
        Abase16 = (const bf16_t*)A + (size_t)(row0 + srow) * K + schnk;
    else
        Abase32 = (const float*)A + (size_t)(row0 + srow) * K + schnk;

    const int fr = lane & 15;
    const int fk = (lane >> 4) * 8;

    for (int k0 = 0; k0 < K; k0 += 32) {
        #pragma unroll
        for (int j2 = 0; j2 < 2; ++j2) {
            const int seg = seg0 + j2;
            if constexpr (sizeof(AT) == 2) {
                async_copy16(Abase16 + (size_t)(seg * 16) * K + k0, sA + seg * 512);
            } else {
                const float* ap = Abase32 + (size_t)(seg * 16) * K + k0;
                float4 u = *(const float4*)ap;
                float4 v = *(const float4*)(ap + 4);
                bf16x8 o;
                o[0] = (__bf16)u.x; o[1] = (__bf16)u.y; o[2] = (__bf16)u.z; o[3] = (__bf16)u.w;
                o[4] = (__bf16)v.x; o[5] = (__bf16)v.y; o[6] = (__bf16)v.z; o[7] = (__bf16)v.w;
                // linear LDS dest matches async layout: byte off = lane*16 within seg
                *(bf16x8*)(sA + seg * 512 + lane * 8) = o;
            }
            async_copy16(Bbase + (size_t)(seg * 16) * K + k0, sB + seg * 512);
        }
        __syncthreads();

        bf16x8 af[4], bfr[4];
        #pragma unroll
        for (int i = 0; i < 4; ++i)
            af[i] = *(const bf16x8*)(sA + (wr + i * 16 + fr) * 32 + fk);
        #pragma unroll
        for (int j = 0; j < 4; ++j)
            bfr[j] = *(const bf16x8*)(sB + (wc + j * 16 + fr) * 32 + fk);

        #pragma unroll
        for (int i = 0; i < 4; ++i)
            #pragma unroll
            for (int j = 0; j < 4; ++j)
                acc[i][j] = __builtin_amdgcn_mfma_f32_16x16x32_bf16(af[i], bfr[j], acc[i][j], 0, 0, 0);
        __syncthreads();
    }

    // epilogue: C/D layout col=lane&15, row=(lane>>4)*4+reg  [m89-verified]
    #pragma unroll
    for (int j = 0; j < 4; ++j) {
        const int gc = col0 + wc + j * 16 + (lane & 15);
        float cb = 0.f;
        if constexpr (BIAS_MODE == 0) cb = bias[gc];
        if constexpr (BIAS_MODE == 2) cb = bias[gc] + bias2[gc];
        #pragma unroll
        for (int i = 0; i < 4; ++i) {
            const int gr0 = row0 + wr + i * 16 + ((lane >> 4) << 2);
            #pragma unroll
            for (int r = 0; r < 4; ++r) {
                const int gr = gr0 + r;
                float v = acc[i][j][r];
                if constexpr (BIAS_MODE == 1)
                    v += bias2[(size_t)(gr >> 3) * N + gc];
                else
                    v += cb;
                C[(size_t)gr * N + gc] = (CT)v;
            }
        }
    }
}

// ---- per-row micro attention: row r of qkv[65536,1536] -> a[65536,512] ----
// q/k/v = row[0:512],[512:1024],[1024:1536], each viewed [8 pos][64 ch].
// S[i][j] = (1/8) * sum_c q[i][c]k[j][c]; P = softmax_j(S); out[i][c]=sum_j P[i][j]v[j][c]
// 1 wave per row; lane = i*8+s (i=query pos, s=8-elem channel chunk)
__global__ __launch_bounds__(256, 4)
void attn_kernel(const bf16_t* __restrict__ qkv, bf16_t* __restrict__ out)
{
    __shared__ bf16_t skv[4][1024];   // per wave: k row [0:512], v row [512:1024]
    const int tid  = threadIdx.x;
    const int wave = tid >> 6;
    const int lane = tid & 63;
    const size_t row = (size_t)blockIdx.x * 4 + wave;

    const bf16_t* base = qkv + row * 1536;
    bf16x8 q8 = *(const bf16x8*)(base + lane * 8);
    bf16x8 k8 = *(const bf16x8*)(base + 512 + lane * 8);
    bf16x8 v8 = *(const bf16x8*)(base + 1024 + lane * 8);
    *(bf16x8*)&skv[wave][lane * 8]       = k8;
    *(bf16x8*)&skv[wave][512 + lane * 8] = v8;

    float q[8];
    #pragma unroll
    for (int e = 0; e < 8; ++e) q[e] = (float)q8[e];
    __syncthreads();

    const int s8 = (lane & 7) * 8;
    float S[8];
    #pragma unroll
    for (int j = 0; j < 8; ++j) {
        bf16x8 kj = *(const bf16x8*)&skv[wave][j * 64 + s8];
        float p = 0.f;
        #pragma unroll
        for (int e = 0; e < 8; ++e) p += q[e] * (float)kj[e];
        p += __shfl_xor(p, 1);
        p += __shfl_xor(p, 2);
        p += __shfl_xor(p, 4);
        S[j] = p * 0.125f;   // (64^-0.25)^2 = 1/8
    }
    float m = S[0];
    #pragma unroll
    for (int j = 1; j < 8; ++j) m = fmaxf(m, S[j]);
    float sum = 0.f;
    #pragma unroll
    for (int j = 0; j < 8; ++j) { S[j] = __expf(S[j] - m); sum += S[j]; }
    const float inv = 1.f / sum;

    float o[8] = {0.f, 0.f, 0.f, 0.f, 0.f, 0.f, 0.f, 0.f};
    #pragma unroll
    for (int j = 0; j < 8; ++j) {
        const float pj = S[j] * inv;
        bf16x8 vj = *(const bf16x8*)&skv[wave][512 + j * 64 + s8];
        #pragma unroll
        for (int e = 0; e < 8; ++e) o[e] += pj * (float)vj[e];
    }
    bf16x8 o8;
    #pragma unroll
    for (int e = 0; e < 8; ++e) o8[e] = (__bf16)o[e];
    *(bf16x8*)(out + row * 512 + lane * 8) = o8;
}

extern "C" void kernel_launch(void* const* d_in, const int* in_sizes, int n_in,
                              void* d_out, int out_size, void* d_ws, size_t ws_size,
                              hipStream_t stream)
{
    const float* x      = (const float*)d_in[0];
    const float* t      = (const float*)d_in[1];
    const float* W_down = (const float*)d_in[2];
    const float* b_down = (const float*)d_in[3];
    const float* W_t    = (const float*)d_in[4];
    const float* b_t    = (const float*)d_in[5];
    const float* W_qkv  = (const float*)d_in[6];
    const float* b_qkv  = (const float*)d_in[7];
    const float* W_out  = (const float*)d_in[8];
    const float* b_out  = (const float*)d_in[9];
    float* out = (float*)d_out;

    char* p = (char*)d_ws;
    // phase-aliased layout (x and t now read fp32 directly in GEMMs):
    bf16_t* qkvm  = (bf16_t*)(p);                 // 201.3 MB
    bf16_t* x1    = (bf16_t*)(p + 201326592);     // 67.1 MB
    bf16_t* am    = (bf16_t*)(p + 268435456);     // 67.1 MB
    float*  tbias = (float*) (p + 343932928);     // 16.8 MB
    bf16_t* wd    = (bf16_t*)(p + 360710144);     // 1.0 MB
    bf16_t* wt    = (bf16_t*)(p + 361758720);     // 0.5 MB
    bf16_t* wq    = (bf16_t*)(p + 362283008);     // 1.5 MB
    bf16_t* wo    = (bf16_t*)(p + 363855872);     // 0.5 MB

    // 1) fp32 -> bf16 weight conversions (x and t converted inline in GEMMs)
    cvt_f32_bf16<<<256, 256, 0, stream>>>(W_down, wd, (long)OUT_CH * IN_CH / 8);
    cvt_f32_bf16<<<128, 256, 0, stream>>>(W_t, wt, (long)OUT_CH * T_DIM / 8);
    cvt_f32_bf16<<<384, 256, 0, stream>>>(W_qkv, wq, (long)3 * OUT_CH * OUT_CH / 8);
    cvt_f32_bf16<<<128, 256, 0, stream>>>(W_out, wo, (long)OUT_CH * OUT_CH / 8);

    // 2) tbias[b][c] = t[b] @ W_t^T + b_t + b_down   (fp32, A read fp32 direct)
    gemm_bt<2, float, float><<<dim3(4, 64), 256, 0, stream>>>(
        t, wt, tbias, b_t, b_down, BS_, OUT_CH, T_DIM);

    // 3) x1 = x @ W_down^T + tbias[row>>3]   (bf16, A read fp32 direct)
    gemm_bt<1, bf16_t, float><<<dim3(4, 512), 256, 0, stream>>>(
        x, wd, x1, nullptr, tbias, N_ROWS, OUT_CH, IN_CH);

    // 4) qkv = x1 @ W_qkv^T + b_qkv   (bf16)
    gemm_bt<0, bf16_t, bf16_t><<<dim3(12, 512), 256, 0, stream>>>(
        x1, wq, qkvm, b_qkv, nullptr, N_ROWS, 3 * OUT_CH, OUT_CH);

    // 5) per-row attention
    attn_kernel<<<16384, 256, 0, stream>>>(qkvm, am);

    // 6) out = a @ W_out^T + b_out   (fp32)
    gemm_bt<0, float, bf16_t><<<dim3(4, 512), 256, 0, stream>>>(
        am, wo, out, b_out, nullptr, N_ROWS, OUT_CH, OUT_CH);
}

// Round 2
// 760.361 us; speedup vs baseline: 1.0152x; 1.0152x over previous
//
#include <hip/hip_runtime.h>
#include <hip/hip_bf16.h>
#include <cstdint>
#include <cstddef>

typedef __bf16 bf16_t;
typedef __bf16 bf16x8 __attribute__((ext_vector_type(8)));
typedef float  f32x4  __attribute__((ext_vector_type(4)));

#define N_ROWS 65536   // BS*CLIP
#define IN_CH  1024
#define OUT_CH 512
#define T_DIM  512
#define BS_    8192

// ---- async global->LDS, 16B per lane (global_load_lds_dwordx4) ----
__device__ __forceinline__ void async_copy16(const bf16_t* g, bf16_t* l) {
    __builtin_amdgcn_global_load_lds(
        (const __attribute__((address_space(1))) void*)(uintptr_t)(g),
        (__attribute__((address_space(3))) void*)(uintptr_t)(l),
        16, 0, 0);
}

// ---- fp32 -> bf16 pack, 8 elems/thread (weights only) ----
__global__ __launch_bounds__(256)
void cvt_f32_bf16(const float* __restrict__ in, bf16_t* __restrict__ out, long n8) {
    long idx = (long)blockIdx.x * 256 + threadIdx.x;
    if (idx >= n8) return;
    const float4* p = (const float4*)(in + idx * 8);
    float4 u = p[0], v = p[1];
    bf16x8 o;
    o[0] = (__bf16)u.x; o[1] = (__bf16)u.y; o[2] = (__bf16)u.z; o[3] = (__bf16)u.w;
    o[4] = (__bf16)v.x; o[5] = (__bf16)v.y; o[6] = (__bf16)v.z; o[7] = (__bf16)v.w;
    *(bf16x8*)(out + idx * 8) = o;
}

// ---- m97-style GEMM: C[M,N] = A[M,K] * B[N,K]^T (+bias) ----
// LDS tile [128 rows][32 k] bf16, 64B row stride.
// T2 bank-conflict fix: 16B chunk c at row r holds logical chunk c ^ ((r>>1)&3).
//   - staged operands (global_load_lds / linear ds_write): pre-swizzle the GLOBAL
//     source chunk per lane: sc = (lane&3) ^ ((lane>>3)&3)   [(lane>>3)&3 == (ldsrow>>1)&3]
//   - fragment reads: phys chunk = (lane>>4) ^ ((fr>>1)&3)   [same involution]
// AT = bf16_t : A staged via global_load_lds (async)
// AT = float  : A loaded fp32 to regs, cvt to bf16, ds_write (fused conversion)
// BIAS_MODE 0: + bias[col]
// BIAS_MODE 1: + bias2[(row>>3)*N + col]   (per-batch time-emb row, b_down folded in)
// BIAS_MODE 2: + bias[col] + bias2[col]
template<int BIAS_MODE, typename CT, typename AT>
__global__ __launch_bounds__(256, 2)
void gemm_bt(const AT* __restrict__ A, const bf16_t* __restrict__ B,
             CT* __restrict__ C,
             const float* __restrict__ bias,
             const float* __restrict__ bias2,
             int M, int N, int K)
{
    __shared__ bf16_t sA[128 * 32];
    __shared__ bf16_t sB[128 * 32];

    const int tid  = threadIdx.x;
    const int wave = tid >> 6;
    const int lane = tid & 63;

    // XCD-aware bijective swizzle (nwg % 8 == 0 for all our launches)
    const unsigned gx  = gridDim.x;
    const unsigned nwg = gx * gridDim.y;
    unsigned bid = blockIdx.y * gx + blockIdx.x;
    if ((nwg & 7u) == 0u) bid = (bid & 7u) * (nwg >> 3) + (bid >> 3);
    const int row0 = (int)(bid / gx) * 128;
    const int col0 = (int)(bid % gx) * 128;

    const int wr = (wave >> 1) * 64;
    const int wc = (wave & 1) * 64;

    f32x4 acc[4][4];
    #pragma unroll
    for (int i = 0; i < 4; ++i)
        #pragma unroll
        for (int j = 0; j < 4; ++j)
            acc[i][j] = (f32x4){0.f, 0.f, 0.f, 0.f};

    // staging: 8 segments of 1KB each for A and B; wave w does segs {2w, 2w+1}
    const int seg0  = wave * 2;
    const int srow  = lane >> 2;                          // row within 16-row segment
    const int sc    = (lane & 3) ^ ((lane >> 3) & 3);     // swizzled 16B chunk index
    const int schnk = sc * 8;                             // k-elem offset

    const bf16_t* Bbase = B + (size_t)col0 * K + (size_t)srow * K + schnk;

    const bf16_t* Abase16 = nullptr;
    const float*  Abase32 = nullptr;
    if constexpr (sizeof(AT) == 2)
        Abase16 = (const bf16_t*)A + (size_t)(row0 + srow) * K + schnk;
    else
        Abase32 = (const float*)A + (size_t)(row0 + srow) * K + schnk;

    const int fr = lane & 15;
    // swizzled fragment chunk: logical chunk (lane>>4) XOR (row>>1)&3 (= (fr>>1)&3)
    const int fk = ((lane >> 4) ^ ((fr >> 1) & 3)) * 8;

    for (int k0 = 0; k0 < K; k0 += 32) {
        #pragma unroll
        for (int j2 = 0; j2 < 2; ++j2) {
            const int seg = seg0 + j2;
            if constexpr (sizeof(AT) == 2) {
                async_copy16(Abase16 + (size_t)(seg * 16) * K + k0, sA + seg * 512);
            } else {
                const float* ap = Abase32 + (size_t)(seg * 16) * K + k0;
                float4 u = *(const float4*)ap;
                float4 v = *(const float4*)(ap + 4);
                bf16x8 o;
                o[0] = (__bf16)u.x; o[1] = (__bf16)u.y; o[2] = (__bf16)u.z; o[3] = (__bf16)u.w;
                o[4] = (__bf16)v.x; o[5] = (__bf16)v.y; o[6] = (__bf16)v.z; o[7] = (__bf16)v.w;
                // linear LDS dest (matches async layout); data is pre-swizzled via source
                *(bf16x8*)(sA + seg * 512 + lane * 8) = o;
            }
            async_copy16(Bbase + (size_t)(seg * 16) * K + k0, sB + seg * 512);
        }
        __syncthreads();

        bf16x8 af[4], bfr[4];
        #pragma unroll
        for (int i = 0; i < 4; ++i)
            af[i] = *(const bf16x8*)(sA + (wr + i * 16 + fr) * 32 + fk);
        #pragma unroll
        for (int j = 0; j < 4; ++j)
            bfr[j] = *(const bf16x8*)(sB + (wc + j * 16 + fr) * 32 + fk);

        #pragma unroll
        for (int i = 0; i < 4; ++i)
            #pragma unroll
            for (int j = 0; j < 4; ++j)
                acc[i][j] = __builtin_amdgcn_mfma_f32_16x16x32_bf16(af[i], bfr[j], acc[i][j], 0, 0, 0);
        __syncthreads();
    }

    // epilogue: C/D layout col=lane&15, row=(lane>>4)*4+reg  [m89-verified]
    #pragma unroll
    for (int j = 0; j < 4; ++j) {
        const int gc = col0 + wc + j * 16 + (lane & 15);
        float cb = 0.f;
        if constexpr (BIAS_MODE == 0) cb = bias[gc];
        if constexpr (BIAS_MODE == 2) cb = bias[gc] + bias2[gc];
        #pragma unroll
        for (int i = 0; i < 4; ++i) {
            const int gr0 = row0 + wr + i * 16 + ((lane >> 4) << 2);
            #pragma unroll
            for (int r = 0; r < 4; ++r) {
                const int gr = gr0 + r;
                float v = acc[i][j][r];
                if constexpr (BIAS_MODE == 1)
                    v += bias2[(size_t)(gr >> 3) * N + gc];
                else
                    v += cb;
                C[(size_t)gr * N + gc] = (CT)v;
            }
        }
    }
}

// ---- per-row micro attention: row r of qkv[65536,1536] -> a[65536,512] ----
// (LDS reads here are 8-lane broadcasts across a 128B span — conflict-free, unchanged)
__global__ __launch_bounds__(256, 4)
void attn_kernel(const bf16_t* __restrict__ qkv, bf16_t* __restrict__ out)
{
    __shared__ bf16_t skv[4][1024];   // per wave: k row [0:512], v row [512:1024]
    const int tid  = threadIdx.x;
    const int wave = tid >> 6;
    const int lane = tid & 63;
    const size_t row = (size_t)blockIdx.x * 4 + wave;

    const bf16_t* base = qkv + row * 1536;
    bf16x8 q8 = *(const bf16x8*)(base + lane * 8);
    bf16x8 k8 = *(const bf16x8*)(base + 512 + lane * 8);
    bf16x8 v8 = *(const bf16x8*)(base + 1024 + lane * 8);
    *(bf16x8*)&skv[wave][lane * 8]       = k8;
    *(bf16x8*)&skv[wave][512 + lane * 8] = v8;

    float q[8];
    #pragma unroll
    for (int e = 0; e < 8; ++e) q[e] = (float)q8[e];
    __syncthreads();

    const int s8 = (lane & 7) * 8;
    float S[8];
    #pragma unroll
    for (int j = 0; j < 8; ++j) {
        bf16x8 kj = *(const bf16x8*)&skv[wave][j * 64 + s8];
        float p = 0.f;
        #pragma unroll
        for (int e = 0; e < 8; ++e) p += q[e] * (float)kj[e];
        p += __shfl_xor(p, 1);
        p += __shfl_xor(p, 2);
        p += __shfl_xor(p, 4);
        S[j] = p * 0.125f;   // (64^-0.25)^2 = 1/8
    }
    float m = S[0];
    #pragma unroll
    for (int j = 1; j < 8; ++j) m = fmaxf(m, S[j]);
    float sum = 0.f;
    #pragma unroll
    for (int j = 0; j < 8; ++j) { S[j] = __expf(S[j] - m); sum += S[j]; }
    const float inv = 1.f / sum;

    float o[8] = {0.f, 0.f, 0.f, 0.f, 0.f, 0.f, 0.f, 0.f};
    #pragma unroll
    for (int j = 0; j < 8; ++j) {
        const float pj = S[j] * inv;
        bf16x8 vj = *(const bf16x8*)&skv[wave][512 + j * 64 + s8];
        #pragma unroll
        for (int e = 0; e < 8; ++e) o[e] += pj * (float)vj[e];
    }
    bf16x8 o8;
    #pragma unroll
    for (int e = 0; e < 8; ++e) o8[e] = (__bf16)o[e];
    *(bf16x8*)(out + row * 512 + lane * 8) = o8;
}

extern "C" void kernel_launch(void* const* d_in, const int* in_sizes, int n_in,
                              void* d_out, int out_size, void* d_ws, size_t ws_size,
                              hipStream_t stream)
{
    const float* x      = (const float*)d_in[0];
    const float* t      = (const float*)d_in[1];
    const float* W_down = (const float*)d_in[2];
    const float* b_down = (const float*)d_in[3];
    const float* W_t    = (const float*)d_in[4];
    const float* b_t    = (const float*)d_in[5];
    const float* W_qkv  = (const float*)d_in[6];
    const float* b_qkv  = (const float*)d_in[7];
    const float* W_out  = (const float*)d_in[8];
    const float* b_out  = (const float*)d_in[9];
    float* out = (float*)d_out;

    char* p = (char*)d_ws;
    bf16_t* qkvm  = (bf16_t*)(p);                 // 201.3 MB
    bf16_t* x1    = (bf16_t*)(p + 201326592);     // 67.1 MB
    bf16_t* am    = (bf16_t*)(p + 268435456);     // 67.1 MB
    float*  tbias = (float*) (p + 343932928);     // 16.8 MB
    bf16_t* wd    = (bf16_t*)(p + 360710144);     // 1.0 MB
    bf16_t* wt    = (bf16_t*)(p + 361758720);     // 0.5 MB
    bf16_t* wq    = (bf16_t*)(p + 362283008);     // 1.5 MB
    bf16_t* wo    = (bf16_t*)(p + 363855872);     // 0.5 MB

    // 1) fp32 -> bf16 weight conversions (x and t converted inline in GEMMs)
    cvt_f32_bf16<<<256, 256, 0, stream>>>(W_down, wd, (long)OUT_CH * IN_CH / 8);
    cvt_f32_bf16<<<128, 256, 0, stream>>>(W_t, wt, (long)OUT_CH * T_DIM / 8);
    cvt_f32_bf16<<<384, 256, 0, stream>>>(W_qkv, wq, (long)3 * OUT_CH * OUT_CH / 8);
    cvt_f32_bf16<<<128, 256, 0, stream>>>(W_out, wo, (long)OUT_CH * OUT_CH / 8);

    // 2) tbias[b][c] = t[b] @ W_t^T + b_t + b_down   (fp32, A read fp32 direct)
    gemm_bt<2, float, float><<<dim3(4, 64), 256, 0, stream>>>(
        t, wt, tbias, b_t, b_down, BS_, OUT_CH, T_DIM);

    // 3) x1 = x @ W_down^T + tbias[row>>3]   (bf16, A read fp32 direct)
    gemm_bt<1, bf16_t, float><<<dim3(4, 512), 256, 0, stream>>>(
        x, wd, x1, nullptr, tbias, N_ROWS, OUT_CH, IN_CH);

    // 4) qkv = x1 @ W_qkv^T + b_qkv   (bf16)
    gemm_bt<0, bf16_t, bf16_t><<<dim3(12, 512), 256, 0, stream>>>(
        x1, wq, qkvm, b_qkv, nullptr, N_ROWS, 3 * OUT_CH, OUT_CH);

    // 5) per-row attention
    attn_kernel<<<16384, 256, 0, stream>>>(qkvm, am);

    // 6) out = a @ W_out^T + b_out   (fp32)
    gemm_bt<0, float, bf16_t><<<dim3(4, 512), 256, 0, stream>>>(
        am, wo, out, b_out, nullptr, N_ROWS, OUT_CH, OUT_CH);
}